// Round 9
// baseline (478.272 us; speedup 1.0000x reference)
//
#include <hip/hip_runtime.h>

// RNNDecoderP round 9: 2-wave pipeline — consumer work folded onto producer waves.
// Round-8 analysis: DS pipe ~73% busy (44 DS instr/CU/step); w1/w3 redundant ring
// reads were half of it. Now each recurrence wave reuses its own post-readback
// registers for the downstream dots, placed in the ds_write->ld16 latency window:
//   w0: L1 recurrence; gx2=Wih2*h1 at 1-step lag (from h1a regs); y drain (lag-2 chunk)
//   w1: L2 recurrence (gx = one b128 pre-produced); MLP head at 1-step lag (from h2a
//       regs), DPP row_ror-reduced to 4 partials/step.
// h1/h2 use single 32-float LDS buffers (own-wave write->read only). 128-thr blocks.

typedef float v2f __attribute__((ext_vector_type(2)));

constexpr int Bn  = 256;
constexpr int Tn  = 2048;
constexpr int Dn  = 64;
constexpr int DBn = 32;
constexpr int Ln  = 2;
constexpr int Gn  = 96;
constexpr int Kc  = 32;     // steps per chunk/phase

#if __has_builtin(__builtin_amdgcn_exp2f)
__device__ __forceinline__ float exp2_fast(float x) { return __builtin_amdgcn_exp2f(x); }
#else
__device__ __forceinline__ float exp2_fast(float x) { return exp2f(x); }
#endif
#if __has_builtin(__builtin_amdgcn_rcpf)
__device__ __forceinline__ float rcp_fast(float x) { return __builtin_amdgcn_rcpf(x); }
#else
__device__ __forceinline__ float rcp_fast(float x) { return 1.0f / x; }
#endif

__device__ __forceinline__ float sigmoid_f(float x) {
  return rcp_fast(1.0f + exp2_fast(-1.4426950408889634f * x));
}
__device__ __forceinline__ float tanh_f(float x) {
  return 1.0f - 2.0f * rcp_fast(1.0f + exp2_fast(2.8853900817779268f * x));
}

template <int CTRL>
__device__ __forceinline__ float dpp_add(float x) {
  int y = __builtin_amdgcn_update_dpp(0, __builtin_bit_cast(int, x), CTRL, 0xf, 0xf, true);
  return x + __builtin_bit_cast(float, y);
}
// cross-half (L^8) combine: row_ror:8
__device__ __forceinline__ float dppx8_add(float x) { return dpp_add<0x128>(x); }
// full 16-lane row sum (all lanes): ror8+ror4+ror2+ror1 circulant reduce
__device__ __forceinline__ float dpp_row_sum16(float x) {
  x = dpp_add<0x128>(x);
  x = dpp_add<0x124>(x);
  x = dpp_add<0x122>(x);
  x = dpp_add<0x121>(x);
  return x;
}

// 16-float half-dot, single chain (off-chain work)
__device__ __forceinline__ float dot8(const v2f* __restrict__ w, const v2f* __restrict__ h) {
  v2f a = {0.0f, 0.0f};
  #pragma unroll
  for (int q = 0; q < 8; ++q) a = __builtin_elementwise_fma(w[q], h[q], a);
  return a.x + a.y;
}
// 16-float half-dot, two chains (on-chain work)
__device__ __forceinline__ float dot8b(const v2f* __restrict__ w, const v2f* __restrict__ h) {
  v2f a = {0.0f, 0.0f}, b = {0.0f, 0.0f};
  #pragma unroll
  for (int q = 0; q < 4; ++q) {
    a = __builtin_elementwise_fma(w[q], h[q], a);
    b = __builtin_elementwise_fma(w[q + 4], h[q + 4], b);
  }
  a = a + b;
  return a.x + a.y;
}

// load 16 consecutive floats (4 x float4) into v2f[8]
__device__ __forceinline__ void ld16(const float* p, v2f* d) {
  #pragma unroll
  for (int q = 0; q < 4; ++q) {
    float4 a = ((const float4*)p)[q];
    d[2*q] = (v2f){a.x, a.y}; d[2*q+1] = (v2f){a.z, a.w};
  }
}

__global__ __launch_bounds__(128, 1)
void rnn_decoder(const int* __restrict__ band_ids, const float* __restrict__ dtime,
                 const float* __restrict__ z_last, const float* __restrict__ projW,
                 const float* __restrict__ projB, const float* __restrict__ Wih,
                 const float* __restrict__ Whh, const float* __restrict__ bih,
                 const float* __restrict__ bhh, const float* __restrict__ mW1,
                 const float* __restrict__ mb1, const float* __restrict__ mW2,
                 const float* __restrict__ mb2, float* __restrict__ out) {
  const int b    = blockIdx.x >> 1;
  const int kb   = blockIdx.x & 1;
  const int tid  = threadIdx.x;              // 0..127
  const int w    = tid >> 6;                 // 0 = L1+gx+drain, 1 = L2+MLP
  const int L    = tid & 63;
  const int e    = (L & 7) | ((L >> 4) << 3);// owned element/gate 0..31
  const int koff = ((L >> 3) & 1) * 16;      // K-half (bit 3 -> DPP partner L^8)

  __shared__ __align__(16) float yd[Tn];               // compacted dtime -> y
  __shared__ __align__(16) float gxr_[2][Kc][DBn][4];  // w0 -> w1 packed input gates
  __shared__ __align__(16) float vr_[2][Kc][4];        // w1 -> w0 y-partials
  __shared__ __align__(16) float h1b[DBn];             // w0 private write->read buf
  __shared__ __align__(16) float h2b[DBn];             // w1 private write->read buf
  __shared__ __align__(16) float xb[DBn], xs[DBn];
  __shared__ __align__(16) float y0f[4];               // MLP(h2=0) partials (n==0)
  __shared__ int nsh;

  const float mb2v = mb2[kb];

  if (w == 0) {
    // ======== setup: compaction, proj fold, affine consts, Whh1 + Wih2 slices ========
    {
      const int*   brow = band_ids + b * Tn;
      const float* drow = dtime    + b * Tn;
      int cnt = 0;
      int4 bcache[8];
      #pragma unroll
      for (int it = 0; it < 8; ++it) {
        int4 v = ((const int4*)(brow + L * 32))[it];
        bcache[it] = v;
        cnt += (v.x == kb) + (v.y == kb) + (v.z == kb) + (v.w == kb);
      }
      int incl = cnt;
      #pragma unroll
      for (int dlt = 1; dlt < 64; dlt <<= 1) {
        int v = __shfl_up(incl, dlt, 64);
        if (L >= dlt) incl += v;
      }
      int off = incl - cnt;
      const int n0 = __shfl(incl, 63, 64);
      #pragma unroll
      for (int it = 0; it < 8; ++it) {
        int4   v  = bcache[it];
        float4 dd = ((const float4*)(drow + L * 32))[it];
        if (v.x == kb) yd[off++] = dd.x;
        if (v.y == kb) yd[off++] = dd.y;
        if (v.z == kb) yd[off++] = dd.z;
        if (v.w == kb) yd[off++] = dd.w;
      }
      if (L == 0) nsh = n0;
    }
    {
      const float* pw = projW + (kb * (Dn + 1)) * DBn + e;
      const float* zl = z_last + b * Dn;
      float acc = 0.0f;
      #pragma unroll 8
      for (int k = 0; k < Dn; ++k) acc = fmaf(zl[k], pw[k * DBn], acc);
      xb[e] = acc + projB[kb * DBn + e];   // partner lanes write identical values
      xs[e] = pw[Dn * DBn];
    }
    __builtin_amdgcn_wave_barrier();
    const float* wih1  = Wih + ((kb * Ln + 0) * Gn) * DBn;
    const float* bih1p = bih + (kb * Ln + 0) * Gn;
    const float* bhh1p = bhh + (kb * Ln + 0) * Gn;
    float gb_r = 0, gb_z = 0, gb_n = 0, gs_r = 0, gs_z = 0, gs_n = 0;
    #pragma unroll 4
    for (int j = 0; j < DBn; ++j) {
      float xbv = xb[j], xsv = xs[j];
      float wr = wih1[(     e) * DBn + j];
      float wz = wih1[(32 + e) * DBn + j];
      float wn = wih1[(64 + e) * DBn + j];
      gb_r = fmaf(wr, xbv, gb_r);  gs_r = fmaf(wr, xsv, gs_r);
      gb_z = fmaf(wz, xbv, gb_z);  gs_z = fmaf(wz, xsv, gs_z);
      gb_n = fmaf(wn, xbv, gb_n);  gs_n = fmaf(wn, xsv, gs_n);
    }
    gb_r += bih1p[e]      + bhh1p[e];
    gb_z += bih1p[32 + e] + bhh1p[32 + e];
    gb_n += bih1p[64 + e];
    const float bhh1n = bhh1p[64 + e];
    v2f w1r[8], w1z[8], w1n[8];
    const float* whh1 = Whh + ((kb * Ln + 0) * Gn) * DBn;
    ld16(whh1 + (     e) * DBn + koff, w1r);
    ld16(whh1 + (32 + e) * DBn + koff, w1z);
    ld16(whh1 + (64 + e) * DBn + koff, w1n);
    v2f ua[8], ub[8], uc[8];   // Wih2 half-rows for gates e, 32+e, 64+e
    const float* wih2 = Wih + ((kb * Ln + 1) * Gn) * DBn;
    ld16(wih2 + (     e) * DBn + koff, ua);
    ld16(wih2 + (32 + e) * DBn + koff, ub);
    ld16(wih2 + (64 + e) * DBn + koff, uc);
    __syncthreads();   // barrier A

    const int n = nsh;
    const int C = (n + Kc - 1) >> 5;
    v2f h1a[8];
    #pragma unroll
    for (int q = 0; q < 8; ++q) h1a[q] = (v2f){0.0f, 0.0f};
    float h1self = 0.0f;
    for (int c = 0; c < C + 2; ++c) {
      if (c < C) {
        const int t0 = c * Kc;
        float* gxo = &gxr_[c & 1][0][0][0];
        for (int k = 0; k < Kc; ++k) {
          float d  = yd[t0 + k];
          // ---- L1 recurrence chain (h1a = h1_{t-1}) ----
          float ar = dot8b(w1r, h1a);
          float az = dot8b(w1z, h1a);
          float an = dot8b(w1n, h1a);
          ar = dppx8_add(ar);
          az = dppx8_add(az);
          an = dppx8_add(an);
          float r1 = sigmoid_f(fmaf(d, gs_r, gb_r) + ar);
          float z1 = sigmoid_f(fmaf(d, gs_z, gb_z) + az);
          float n1 = tanh_f(fmaf(d, gs_n, gb_n) + r1 * (an + bhh1n));
          float h1new = fmaf(z1, h1self - n1, n1);
          h1b[e] = h1new;                      // ds_write (partner duplicates)
          __builtin_amdgcn_wave_barrier();
          // ---- off-chain filler in the write->read window: gx for step t-1 ----
          if (k >= 1) {
            float g0 = dot8(ua, h1a);
            float g1 = dot8(ub, h1a);
            float g2 = dot8(uc, h1a);
            g0 = dppx8_add(g0);
            g1 = dppx8_add(g1);
            g2 = dppx8_add(g2);
            float4 gv; gv.x = g0; gv.y = g1; gv.z = g2; gv.w = 0.0f;
            *(float4*)&gxo[(k - 1) * DBn * 4 + e * 4] = gv;
          }
          h1self = h1new;
          ld16(&h1b[koff], h1a);               // h1a = h1_t
        }
        // tail: gx for step t0+31 from h1a
        {
          float g0 = dot8(ua, h1a);
          float g1 = dot8(ub, h1a);
          float g2 = dot8(uc, h1a);
          g0 = dppx8_add(g0);
          g1 = dppx8_add(g1);
          g2 = dppx8_add(g2);
          float4 gv; gv.x = g0; gv.y = g1; gv.z = g2; gv.w = 0.0f;
          *(float4*)&gxo[(Kc - 1) * DBn * 4 + e * 4] = gv;
        }
      }
      // ---- y drain for chunk c-2 ----
      if (c >= 2) {
        const int cd = c - 2;
        if (cd < C && L < 32) {
          float4 p = *(const float4*)&vr_[cd & 1][L][0];
          yd[cd * Kc + L] = ((p.x + p.y) + (p.z + p.w)) + mb2v;
        }
      }
      __syncthreads();
    }
  } else {
    // ======== setup: Whh2 half-rows, mW1 half-column, biases, n==0 fallback ========
    const float* whh2  = Whh + ((kb * Ln + 1) * Gn) * DBn;
    const float* bih2p = bih + (kb * Ln + 1) * Gn;
    const float* bhh2p = bhh + (kb * Ln + 1) * Gn;
    v2f r2w[8], z2w[8], n2w[8], m1c[8];
    ld16(whh2 + (     e) * DBn + koff, r2w);
    ld16(whh2 + (32 + e) * DBn + koff, z2w);
    ld16(whh2 + (64 + e) * DBn + koff, n2w);
    #pragma unroll
    for (int q = 0; q < 8; ++q)
      m1c[q] = (v2f){ mW1[(kb * DBn + koff + 2*q)     * DBn + e],
                      mW1[(kb * DBn + koff + 2*q + 1) * DBn + e] };
    const float c2r   = bih2p[e]      + bhh2p[e];
    const float c2z   = bih2p[32 + e] + bhh2p[32 + e];
    const float bih2n = bih2p[64 + e];
    const float bhh2n = bhh2p[64 + e];
    const float mb1e  = mb1[kb * DBn + e];
    const float mW2h  = 0.5f * mW2[kb * DBn + e];   // 0.5: each e counted twice
    {
      float p = fmaxf(mb1e, 0.0f) * mW2h;
      p = dpp_row_sum16(p);
      if ((L & 15) == 15) y0f[L >> 4] = p;
    }
    __syncthreads();   // barrier A

    const int n = nsh;
    const int C = (n + Kc - 1) >> 5;
    v2f h2a[8];
    #pragma unroll
    for (int q = 0; q < 8; ++q) h2a[q] = (v2f){0.0f, 0.0f};
    float h2self = 0.0f;
    for (int c = 0; c < C + 2; ++c) {
      if (c >= 1 && c <= C) {
        const int cc = c - 1;
        const float* gx = &gxr_[cc & 1][0][0][0];
        for (int k = 0; k < Kc; ++k) {
          float4 g = *(const float4*)&gx[k * DBn * 4 + e * 4];   // pre-produced
          // ---- L2 recurrence chain (h2a = h2_{t-1}) ----
          float cr = dot8b(r2w, h2a);
          float cz = dot8b(z2w, h2a);
          float cn = dot8b(n2w, h2a);
          cr = dppx8_add(cr);
          cz = dppx8_add(cz);
          cn = dppx8_add(cn);
          float r2v = sigmoid_f(g.x + cr + c2r);
          float z2v = sigmoid_f(g.y + cz + c2z);
          float n2v = tanh_f(g.z + bih2n + r2v * (cn + bhh2n));
          float h2new = fmaf(z2v, h2self - n2v, n2v);
          h2b[e] = h2new;                      // ds_write
          __builtin_amdgcn_wave_barrier();
          // ---- off-chain filler: MLP head for step t-1 (from h2a) ----
          if (k >= 1) {
            float mh = dot8(m1c, h2a);
            mh = dppx8_add(mh);
            float v = fmaxf(mh + mb1e, 0.0f) * mW2h;
            v = dpp_row_sum16(v);
            if ((L & 15) == 15) vr_[cc & 1][k - 1][L >> 4] = v;
          }
          h2self = h2new;
          ld16(&h2b[koff], h2a);               // h2a = h2_t
        }
        // tail: MLP for step cc*Kc+31 from h2a
        {
          float mh = dot8(m1c, h2a);
          mh = dppx8_add(mh);
          float v = fmaxf(mh + mb1e, 0.0f) * mW2h;
          v = dpp_row_sum16(v);
          if ((L & 15) == 15) vr_[cc & 1][Kc - 1][L >> 4] = v;
        }
      }
      __syncthreads();
    }
  }

  // ================= joint epilogue =================
  const int n = nsh;
  float ylast;
  if (n > 0) {
    ylast = yd[n - 1];
  } else {
    float4 p = *(const float4*)&y0f[0];
    ylast = ((p.x + p.y) + (p.z + p.w)) + mb2v;
  }
  for (int t = n + tid; t < Tn; t += 128) yd[t] = ylast;
  __syncthreads();

  float* orow = out + (kb * Bn + b) * Tn;
  for (int q = tid; q < Tn / 4; q += 128)
    ((float4*)orow)[q] = ((const float4*)yd)[q];
}

extern "C" void kernel_launch(void* const* d_in, const int* in_sizes, int n_in,
                              void* d_out, int out_size, void* d_ws, size_t ws_size,
                              hipStream_t stream) {
  const int*   band_ids = (const int*)  d_in[0];
  const float* dtime    = (const float*)d_in[1];
  const float* z_last   = (const float*)d_in[2];
  const float* projW    = (const float*)d_in[3];
  const float* projB    = (const float*)d_in[4];
  const float* Wih      = (const float*)d_in[5];
  const float* Whh      = (const float*)d_in[6];
  const float* bihp     = (const float*)d_in[7];
  const float* bhhp     = (const float*)d_in[8];
  const float* mW1      = (const float*)d_in[9];
  const float* mb1      = (const float*)d_in[10];
  const float* mW2      = (const float*)d_in[11];
  const float* mb2      = (const float*)d_in[12];
  float* out = (float*)d_out;
  rnn_decoder<<<dim3(Bn * 2), dim3(128), 0, stream>>>(
      band_ids, dtime, z_last, projW, projB, Wih, Whh, bihp, bhhp,
      mW1, mb1, mW2, mb2, out);
}

// Round 10
// 472.180 us; speedup vs baseline: 1.0129x; 1.0129x over previous
//
#include <hip/hip_runtime.h>

// RNNDecoderP round 10: round-9's 2-wave fold, FIXED with ping-pong registers.
// r9 failed because the filler (gx/MLP) read h1a/h2a while ld16 wrote the same
// regs -> WAR serialized the readback behind the filler (918 cyc/step). Now the
// loop is manually unrolled x2 with alternating hA/hB sets: dots from CUR,
// gates, ds_write, ld16 -> NXT (issues immediately; no WAR), filler from CUR
// during the read latency.
//   w0: L1 recurrence + gx2=Wih2*h1 (1-step lag, from CUR) + y drain (lag-2 chunk)
//   w1: L2 recurrence (gx = one pre-produced b128) + MLP head (1-step lag, DPP
//       row-sum -> 4 partials/step)
// DS ~14 instr/block-step (r8: 22), 3 blocks/CU. Register gamble: w0 ~150 live.

typedef float v2f __attribute__((ext_vector_type(2)));

constexpr int Bn  = 256;
constexpr int Tn  = 2048;
constexpr int Dn  = 64;
constexpr int DBn = 32;
constexpr int Ln  = 2;
constexpr int Gn  = 96;
constexpr int Kc  = 32;     // steps per chunk/phase (even!)

#if __has_builtin(__builtin_amdgcn_exp2f)
__device__ __forceinline__ float exp2_fast(float x) { return __builtin_amdgcn_exp2f(x); }
#else
__device__ __forceinline__ float exp2_fast(float x) { return exp2f(x); }
#endif
#if __has_builtin(__builtin_amdgcn_rcpf)
__device__ __forceinline__ float rcp_fast(float x) { return __builtin_amdgcn_rcpf(x); }
#else
__device__ __forceinline__ float rcp_fast(float x) { return 1.0f / x; }
#endif

__device__ __forceinline__ float sigmoid_f(float x) {
  return rcp_fast(1.0f + exp2_fast(-1.4426950408889634f * x));
}
__device__ __forceinline__ float tanh_f(float x) {
  return 1.0f - 2.0f * rcp_fast(1.0f + exp2_fast(2.8853900817779268f * x));
}

template <int CTRL>
__device__ __forceinline__ float dpp_add(float x) {
  int y = __builtin_amdgcn_update_dpp(0, __builtin_bit_cast(int, x), CTRL, 0xf, 0xf, true);
  return x + __builtin_bit_cast(float, y);
}
__device__ __forceinline__ float dppx8_add(float x) { return dpp_add<0x128>(x); }
__device__ __forceinline__ float dpp_row_sum16(float x) {
  x = dpp_add<0x128>(x);
  x = dpp_add<0x124>(x);
  x = dpp_add<0x122>(x);
  x = dpp_add<0x121>(x);
  return x;
}

__device__ __forceinline__ float dot8(const v2f* __restrict__ w, const v2f* __restrict__ h) {
  v2f a = {0.0f, 0.0f};
  #pragma unroll
  for (int q = 0; q < 8; ++q) a = __builtin_elementwise_fma(w[q], h[q], a);
  return a.x + a.y;
}
__device__ __forceinline__ float dot8b(const v2f* __restrict__ w, const v2f* __restrict__ h) {
  v2f a = {0.0f, 0.0f}, b = {0.0f, 0.0f};
  #pragma unroll
  for (int q = 0; q < 4; ++q) {
    a = __builtin_elementwise_fma(w[q], h[q], a);
    b = __builtin_elementwise_fma(w[q + 4], h[q + 4], b);
  }
  a = a + b;
  return a.x + a.y;
}

__device__ __forceinline__ void ld16(const float* p, v2f* d) {
  #pragma unroll
  for (int q = 0; q < 4; ++q) {
    float4 a = ((const float4*)p)[q];
    d[2*q] = (v2f){a.x, a.y}; d[2*q+1] = (v2f){a.z, a.w};
  }
}

__global__ __launch_bounds__(128, 1)
void rnn_decoder(const int* __restrict__ band_ids, const float* __restrict__ dtime,
                 const float* __restrict__ z_last, const float* __restrict__ projW,
                 const float* __restrict__ projB, const float* __restrict__ Wih,
                 const float* __restrict__ Whh, const float* __restrict__ bih,
                 const float* __restrict__ bhh, const float* __restrict__ mW1,
                 const float* __restrict__ mb1, const float* __restrict__ mW2,
                 const float* __restrict__ mb2, float* __restrict__ out) {
  const int b    = blockIdx.x >> 1;
  const int kb   = blockIdx.x & 1;
  const int tid  = threadIdx.x;              // 0..127
  const int w    = tid >> 6;                 // 0 = L1+gx+drain, 1 = L2+MLP
  const int L    = tid & 63;
  const int e    = (L & 7) | ((L >> 4) << 3);// owned element/gate 0..31
  const int koff = ((L >> 3) & 1) * 16;      // K-half (bit 3 -> DPP partner L^8)

  __shared__ __align__(16) float yd[Tn];               // compacted dtime -> y
  __shared__ __align__(16) float gxr_[2][Kc][DBn][4];  // w0 -> w1 packed input gates
  __shared__ __align__(16) float vr_[2][Kc][4];        // w1 -> w0 y-partials
  __shared__ __align__(16) float h1b[DBn];             // w0 private write->read buf
  __shared__ __align__(16) float h2b[DBn];             // w1 private write->read buf
  __shared__ __align__(16) float xb[DBn], xs[DBn];
  __shared__ __align__(16) float y0f[4];               // MLP(h2=0) partials (n==0)
  __shared__ int nsh;

  const float mb2v = mb2[kb];

  if (w == 0) {
    // ======== setup: compaction, proj fold, affine consts, Whh1 + Wih2 slices ========
    {
      const int*   brow = band_ids + b * Tn;
      const float* drow = dtime    + b * Tn;
      int cnt = 0;
      int4 bcache[8];
      #pragma unroll
      for (int it = 0; it < 8; ++it) {
        int4 v = ((const int4*)(brow + L * 32))[it];
        bcache[it] = v;
        cnt += (v.x == kb) + (v.y == kb) + (v.z == kb) + (v.w == kb);
      }
      int incl = cnt;
      #pragma unroll
      for (int dlt = 1; dlt < 64; dlt <<= 1) {
        int v = __shfl_up(incl, dlt, 64);
        if (L >= dlt) incl += v;
      }
      int off = incl - cnt;
      const int n0 = __shfl(incl, 63, 64);
      #pragma unroll
      for (int it = 0; it < 8; ++it) {
        int4   v  = bcache[it];
        float4 dd = ((const float4*)(drow + L * 32))[it];
        if (v.x == kb) yd[off++] = dd.x;
        if (v.y == kb) yd[off++] = dd.y;
        if (v.z == kb) yd[off++] = dd.z;
        if (v.w == kb) yd[off++] = dd.w;
      }
      if (L == 0) nsh = n0;
    }
    {
      const float* pw = projW + (kb * (Dn + 1)) * DBn + e;
      const float* zl = z_last + b * Dn;
      float acc = 0.0f;
      #pragma unroll 8
      for (int k = 0; k < Dn; ++k) acc = fmaf(zl[k], pw[k * DBn], acc);
      xb[e] = acc + projB[kb * DBn + e];
      xs[e] = pw[Dn * DBn];
    }
    __builtin_amdgcn_wave_barrier();
    const float* wih1  = Wih + ((kb * Ln + 0) * Gn) * DBn;
    const float* bih1p = bih + (kb * Ln + 0) * Gn;
    const float* bhh1p = bhh + (kb * Ln + 0) * Gn;
    float gb_r = 0, gb_z = 0, gb_n = 0, gs_r = 0, gs_z = 0, gs_n = 0;
    #pragma unroll 4
    for (int j = 0; j < DBn; ++j) {
      float xbv = xb[j], xsv = xs[j];
      float wr = wih1[(     e) * DBn + j];
      float wz = wih1[(32 + e) * DBn + j];
      float wn = wih1[(64 + e) * DBn + j];
      gb_r = fmaf(wr, xbv, gb_r);  gs_r = fmaf(wr, xsv, gs_r);
      gb_z = fmaf(wz, xbv, gb_z);  gs_z = fmaf(wz, xsv, gs_z);
      gb_n = fmaf(wn, xbv, gb_n);  gs_n = fmaf(wn, xsv, gs_n);
    }
    gb_r += bih1p[e]      + bhh1p[e];
    gb_z += bih1p[32 + e] + bhh1p[32 + e];
    gb_n += bih1p[64 + e];
    const float bhh1n = bhh1p[64 + e];
    v2f w1r[8], w1z[8], w1n[8];
    const float* whh1 = Whh + ((kb * Ln + 0) * Gn) * DBn;
    ld16(whh1 + (     e) * DBn + koff, w1r);
    ld16(whh1 + (32 + e) * DBn + koff, w1z);
    ld16(whh1 + (64 + e) * DBn + koff, w1n);
    v2f ua[8], ub[8], uc[8];   // Wih2 half-rows
    const float* wih2 = Wih + ((kb * Ln + 1) * Gn) * DBn;
    ld16(wih2 + (     e) * DBn + koff, ua);
    ld16(wih2 + (32 + e) * DBn + koff, ub);
    ld16(wih2 + (64 + e) * DBn + koff, uc);
    __syncthreads();   // barrier A

    const int n = nsh;
    const int C = (n + Kc - 1) >> 5;
    v2f h1A[8], h1B[8];
    #pragma unroll
    for (int q = 0; q < 8; ++q) { h1A[q] = (v2f){0.0f, 0.0f}; h1B[q] = (v2f){0.0f, 0.0f}; }
    float h1self = 0.0f;

    // one L1 step: dots from CUR, write, ld16 -> NXT (no WAR), filler gx from CUR
#define L1_STEP(K, CUR, NXT)                                                   \
    {                                                                          \
      float d  = yd[t0 + (K)];                                                 \
      float ar = dot8b(w1r, CUR);                                              \
      float az = dot8b(w1z, CUR);                                              \
      float an = dot8b(w1n, CUR);                                              \
      ar = dppx8_add(ar);                                                      \
      az = dppx8_add(az);                                                      \
      an = dppx8_add(an);                                                      \
      float r1 = sigmoid_f(fmaf(d, gs_r, gb_r) + ar);                          \
      float z1 = sigmoid_f(fmaf(d, gs_z, gb_z) + az);                          \
      float n1 = tanh_f(fmaf(d, gs_n, gb_n) + r1 * (an + bhh1n));              \
      float h1new = fmaf(z1, h1self - n1, n1);                                 \
      h1b[e] = h1new;                                                          \
      __builtin_amdgcn_wave_barrier();                                         \
      ld16(&h1b[koff], NXT);                                                   \
      if ((K) >= 1) {                                                          \
        float g0 = dot8(ua, CUR);                                              \
        float g1 = dot8(ub, CUR);                                              \
        float g2 = dot8(uc, CUR);                                              \
        g0 = dppx8_add(g0);                                                    \
        g1 = dppx8_add(g1);                                                    \
        g2 = dppx8_add(g2);                                                    \
        float4 gv; gv.x = g0; gv.y = g1; gv.z = g2; gv.w = 0.0f;               \
        *(float4*)&gxo[((K) - 1) * DBn * 4 + e * 4] = gv;                      \
      }                                                                        \
      h1self = h1new;                                                          \
    }

    for (int c = 0; c < C + 2; ++c) {
      if (c < C) {
        const int t0 = c * Kc;
        float* gxo = &gxr_[c & 1][0][0][0];
        for (int k = 0; k < Kc; k += 2) {
          L1_STEP(k,     h1A, h1B)
          L1_STEP(k + 1, h1B, h1A)
        }
        // tail: gx for step t0+Kc-1 from h1A (CUR after even count of swaps)
        {
          float g0 = dot8(ua, h1A);
          float g1 = dot8(ub, h1A);
          float g2 = dot8(uc, h1A);
          g0 = dppx8_add(g0);
          g1 = dppx8_add(g1);
          g2 = dppx8_add(g2);
          float4 gv; gv.x = g0; gv.y = g1; gv.z = g2; gv.w = 0.0f;
          *(float4*)&gxo[(Kc - 1) * DBn * 4 + e * 4] = gv;
        }
      }
      // ---- y drain for chunk c-2 ----
      if (c >= 2) {
        const int cd = c - 2;
        if (cd < C && L < 32) {
          float4 p = *(const float4*)&vr_[cd & 1][L][0];
          yd[cd * Kc + L] = ((p.x + p.y) + (p.z + p.w)) + mb2v;
        }
      }
      __syncthreads();
    }
#undef L1_STEP
  } else {
    // ======== setup: Whh2 half-rows, mW1 half-column, biases, n==0 fallback ========
    const float* whh2  = Whh + ((kb * Ln + 1) * Gn) * DBn;
    const float* bih2p = bih + (kb * Ln + 1) * Gn;
    const float* bhh2p = bhh + (kb * Ln + 1) * Gn;
    v2f r2w[8], z2w[8], n2w[8], m1c[8];
    ld16(whh2 + (     e) * DBn + koff, r2w);
    ld16(whh2 + (32 + e) * DBn + koff, z2w);
    ld16(whh2 + (64 + e) * DBn + koff, n2w);
    #pragma unroll
    for (int q = 0; q < 8; ++q)
      m1c[q] = (v2f){ mW1[(kb * DBn + koff + 2*q)     * DBn + e],
                      mW1[(kb * DBn + koff + 2*q + 1) * DBn + e] };
    const float c2r   = bih2p[e]      + bhh2p[e];
    const float c2z   = bih2p[32 + e] + bhh2p[32 + e];
    const float bih2n = bih2p[64 + e];
    const float bhh2n = bhh2p[64 + e];
    const float mb1e  = mb1[kb * DBn + e];
    const float mW2h  = 0.5f * mW2[kb * DBn + e];   // 0.5: each e counted twice/row
    {
      float p = fmaxf(mb1e, 0.0f) * mW2h;
      p = dpp_row_sum16(p);
      if ((L & 15) == 15) y0f[L >> 4] = p;
    }
    __syncthreads();   // barrier A

    const int n = nsh;
    const int C = (n + Kc - 1) >> 5;
    v2f h2A[8], h2B[8];
    #pragma unroll
    for (int q = 0; q < 8; ++q) { h2A[q] = (v2f){0.0f, 0.0f}; h2B[q] = (v2f){0.0f, 0.0f}; }
    float h2self = 0.0f;

#define L2_STEP(K, CUR, NXT)                                                   \
    {                                                                          \
      float4 g = *(const float4*)&gx[(K) * DBn * 4 + e * 4];                   \
      float cr = dot8b(r2w, CUR);                                              \
      float cz = dot8b(z2w, CUR);                                              \
      float cn = dot8b(n2w, CUR);                                              \
      cr = dppx8_add(cr);                                                      \
      cz = dppx8_add(cz);                                                      \
      cn = dppx8_add(cn);                                                      \
      float r2v = sigmoid_f(g.x + cr + c2r);                                   \
      float z2v = sigmoid_f(g.y + cz + c2z);                                   \
      float n2v = tanh_f(g.z + bih2n + r2v * (cn + bhh2n));                    \
      float h2new = fmaf(z2v, h2self - n2v, n2v);                              \
      h2b[e] = h2new;                                                          \
      __builtin_amdgcn_wave_barrier();                                         \
      ld16(&h2b[koff], NXT);                                                   \
      if ((K) >= 1) {                                                          \
        float mh = dot8(m1c, CUR);                                             \
        mh = dppx8_add(mh);                                                    \
        float v = fmaxf(mh + mb1e, 0.0f) * mW2h;                               \
        v = dpp_row_sum16(v);                                                  \
        if ((L & 15) == 15) vr_[cc & 1][(K) - 1][L >> 4] = v;                  \
      }                                                                        \
      h2self = h2new;                                                          \
    }

    for (int c = 0; c < C + 2; ++c) {
      if (c >= 1 && c <= C) {
        const int cc = c - 1;
        const float* gx = &gxr_[cc & 1][0][0][0];
        for (int k = 0; k < Kc; k += 2) {
          L2_STEP(k,     h2A, h2B)
          L2_STEP(k + 1, h2B, h2A)
        }
        // tail: MLP for step cc*Kc+Kc-1 from h2A
        {
          float mh = dot8(m1c, h2A);
          mh = dppx8_add(mh);
          float v = fmaxf(mh + mb1e, 0.0f) * mW2h;
          v = dpp_row_sum16(v);
          if ((L & 15) == 15) vr_[cc & 1][Kc - 1][L >> 4] = v;
        }
      }
      __syncthreads();
    }
#undef L2_STEP
  }

  // ================= joint epilogue =================
  const int n = nsh;
  float ylast;
  if (n > 0) {
    ylast = yd[n - 1];
  } else {
    float4 p = *(const float4*)&y0f[0];
    ylast = ((p.x + p.y) + (p.z + p.w)) + mb2v;
  }
  for (int t = n + tid; t < Tn; t += 128) yd[t] = ylast;
  __syncthreads();

  float* orow = out + (kb * Bn + b) * Tn;
  for (int q = tid; q < Tn / 4; q += 128)
    ((float4*)orow)[q] = ((const float4*)yd)[q];
}

extern "C" void kernel_launch(void* const* d_in, const int* in_sizes, int n_in,
                              void* d_out, int out_size, void* d_ws, size_t ws_size,
                              hipStream_t stream) {
  const int*   band_ids = (const int*)  d_in[0];
  const float* dtime    = (const float*)d_in[1];
  const float* z_last   = (const float*)d_in[2];
  const float* projW    = (const float*)d_in[3];
  const float* projB    = (const float*)d_in[4];
  const float* Wih      = (const float*)d_in[5];
  const float* Whh      = (const float*)d_in[6];
  const float* bihp     = (const float*)d_in[7];
  const float* bhhp     = (const float*)d_in[8];
  const float* mW1      = (const float*)d_in[9];
  const float* mb1      = (const float*)d_in[10];
  const float* mW2      = (const float*)d_in[11];
  const float* mb2      = (const float*)d_in[12];
  float* out = (float*)d_out;
  rnn_decoder<<<dim3(Bn * 2), dim3(128), 0, stream>>>(
      band_ids, dtime, z_last, projW, projB, Wih, Whh, bihp, bhhp,
      mW1, mb1, mW2, mb2, out);
}

// Round 11
// 425.420 us; speedup vs baseline: 1.1242x; 1.1099x over previous
//
#include <hip/hip_runtime.h>

// RNNDecoderP round 11: r8 skeleton (best, 286us), 3 waves/seq.
// w0: L1 recurrence (pure; yd batched float4/4steps). demand ~85 regs.
// w1: gx2=Wih2*h1 producer (lag-1 chunk) + y drain (lag-3 chunk).
// w2: L2 recurrence + MLP filler with r10's ping-pong (h2A/h2B; filler reads CUR
//     while ld16 targets NXT -> no WAR). demand ~106 regs — the measured gamble:
//     r8 fits 88; r10's 150 triggered on-chain reloads. Watch VGPR_Count.
// DS/seq-step 22 -> ~17 (w3's 4 redundant b128 reads + extra wave eliminated).

typedef float v2f __attribute__((ext_vector_type(2)));

constexpr int Bn  = 256;
constexpr int Tn  = 2048;
constexpr int Dn  = 64;
constexpr int DBn = 32;
constexpr int Ln  = 2;
constexpr int Gn  = 96;
constexpr int Kc  = 32;     // steps per chunk/phase (multiple of 4)

#if __has_builtin(__builtin_amdgcn_exp2f)
__device__ __forceinline__ float exp2_fast(float x) { return __builtin_amdgcn_exp2f(x); }
#else
__device__ __forceinline__ float exp2_fast(float x) { return exp2f(x); }
#endif
#if __has_builtin(__builtin_amdgcn_rcpf)
__device__ __forceinline__ float rcp_fast(float x) { return __builtin_amdgcn_rcpf(x); }
#else
__device__ __forceinline__ float rcp_fast(float x) { return 1.0f / x; }
#endif

__device__ __forceinline__ float sigmoid_f(float x) {
  return rcp_fast(1.0f + exp2_fast(-1.4426950408889634f * x));
}
__device__ __forceinline__ float tanh_f(float x) {
  return 1.0f - 2.0f * rcp_fast(1.0f + exp2_fast(2.8853900817779268f * x));
}

template <int CTRL>
__device__ __forceinline__ float dpp_add(float x) {
  int y = __builtin_amdgcn_update_dpp(0, __builtin_bit_cast(int, x), CTRL, 0xf, 0xf, true);
  return x + __builtin_bit_cast(float, y);
}
__device__ __forceinline__ float dppx8_add(float x) { return dpp_add<0x128>(x); }
__device__ __forceinline__ float dpp_row_sum16(float x) {
  x = dpp_add<0x128>(x);
  x = dpp_add<0x124>(x);
  x = dpp_add<0x122>(x);
  x = dpp_add<0x121>(x);
  return x;
}

__device__ __forceinline__ float dot8(const v2f* __restrict__ w, const v2f* __restrict__ h) {
  v2f a = {0.0f, 0.0f};
  #pragma unroll
  for (int q = 0; q < 8; ++q) a = __builtin_elementwise_fma(w[q], h[q], a);
  return a.x + a.y;
}
__device__ __forceinline__ float dot8b(const v2f* __restrict__ w, const v2f* __restrict__ h) {
  v2f a = {0.0f, 0.0f}, b = {0.0f, 0.0f};
  #pragma unroll
  for (int q = 0; q < 4; ++q) {
    a = __builtin_elementwise_fma(w[q], h[q], a);
    b = __builtin_elementwise_fma(w[q + 4], h[q + 4], b);
  }
  a = a + b;
  return a.x + a.y;
}

__device__ __forceinline__ void ld16(const float* p, v2f* d) {
  #pragma unroll
  for (int q = 0; q < 4; ++q) {
    float4 a = ((const float4*)p)[q];
    d[2*q] = (v2f){a.x, a.y}; d[2*q+1] = (v2f){a.z, a.w};
  }
}

__global__ __launch_bounds__(192, 1)
void rnn_decoder(const int* __restrict__ band_ids, const float* __restrict__ dtime,
                 const float* __restrict__ z_last, const float* __restrict__ projW,
                 const float* __restrict__ projB, const float* __restrict__ Wih,
                 const float* __restrict__ Whh, const float* __restrict__ bih,
                 const float* __restrict__ bhh, const float* __restrict__ mW1,
                 const float* __restrict__ mb1, const float* __restrict__ mW2,
                 const float* __restrict__ mb2, float* __restrict__ out) {
  const int b    = blockIdx.x >> 1;
  const int kb   = blockIdx.x & 1;
  const int tid  = threadIdx.x;              // 0..191
  const int w    = tid >> 6;                 // 0=L1, 1=gx+drain, 2=L2+MLP
  const int L    = tid & 63;
  const int e    = (L & 7) | ((L >> 4) << 3);// owned element/gate 0..31
  const int koff = ((L >> 3) & 1) * 16;      // K-half (bit 3 -> DPP partner L^8)

  __shared__ __align__(16) float yd[Tn];               // compacted dtime -> y
  __shared__ __align__(16) float gxr_[2][Kc][DBn][4];  // w1 -> w2 packed input gates
  __shared__ __align__(16) float h1r_[2][Kc][DBn];     // w0 -> w1 ring
  __shared__ __align__(16) float vr_[2][Kc][4];        // w2 -> w1 y-partials
  __shared__ __align__(16) float h2b[DBn];             // w2 private write->read buf
  __shared__ __align__(16) float xb[DBn], xs[DBn];
  __shared__ __align__(16) float y0f[4];               // MLP(h2=0) partials (n==0)
  __shared__ int nsh;

  const float mb2v = mb2[kb];

  if (w == 0) {
    // ======== setup: compaction, proj fold, affine consts, Whh1 slices ========
    {
      const int*   brow = band_ids + b * Tn;
      const float* drow = dtime    + b * Tn;
      int cnt = 0;
      int4 bcache[8];
      #pragma unroll
      for (int it = 0; it < 8; ++it) {
        int4 v = ((const int4*)(brow + L * 32))[it];
        bcache[it] = v;
        cnt += (v.x == kb) + (v.y == kb) + (v.z == kb) + (v.w == kb);
      }
      int incl = cnt;
      #pragma unroll
      for (int dlt = 1; dlt < 64; dlt <<= 1) {
        int v = __shfl_up(incl, dlt, 64);
        if (L >= dlt) incl += v;
      }
      int off = incl - cnt;
      const int n0 = __shfl(incl, 63, 64);
      #pragma unroll
      for (int it = 0; it < 8; ++it) {
        int4   v  = bcache[it];
        float4 dd = ((const float4*)(drow + L * 32))[it];
        if (v.x == kb) yd[off++] = dd.x;
        if (v.y == kb) yd[off++] = dd.y;
        if (v.z == kb) yd[off++] = dd.z;
        if (v.w == kb) yd[off++] = dd.w;
      }
      if (L == 0) nsh = n0;
    }
    {
      const float* pw = projW + (kb * (Dn + 1)) * DBn + e;
      const float* zl = z_last + b * Dn;
      float acc = 0.0f;
      #pragma unroll 8
      for (int k = 0; k < Dn; ++k) acc = fmaf(zl[k], pw[k * DBn], acc);
      xb[e] = acc + projB[kb * DBn + e];
      xs[e] = pw[Dn * DBn];
    }
    __builtin_amdgcn_wave_barrier();
    const float* wih1  = Wih + ((kb * Ln + 0) * Gn) * DBn;
    const float* bih1p = bih + (kb * Ln + 0) * Gn;
    const float* bhh1p = bhh + (kb * Ln + 0) * Gn;
    float gb_r = 0, gb_z = 0, gb_n = 0, gs_r = 0, gs_z = 0, gs_n = 0;
    #pragma unroll 4
    for (int j = 0; j < DBn; ++j) {
      float xbv = xb[j], xsv = xs[j];
      float wr = wih1[(     e) * DBn + j];
      float wz = wih1[(32 + e) * DBn + j];
      float wn = wih1[(64 + e) * DBn + j];
      gb_r = fmaf(wr, xbv, gb_r);  gs_r = fmaf(wr, xsv, gs_r);
      gb_z = fmaf(wz, xbv, gb_z);  gs_z = fmaf(wz, xsv, gs_z);
      gb_n = fmaf(wn, xbv, gb_n);  gs_n = fmaf(wn, xsv, gs_n);
    }
    gb_r += bih1p[e]      + bhh1p[e];
    gb_z += bih1p[32 + e] + bhh1p[32 + e];
    gb_n += bih1p[64 + e];
    const float bhh1n = bhh1p[64 + e];
    v2f w1r[8], w1z[8], w1n[8];
    const float* whh1 = Whh + ((kb * Ln + 0) * Gn) * DBn;
    ld16(whh1 + (     e) * DBn + koff, w1r);
    ld16(whh1 + (32 + e) * DBn + koff, w1z);
    ld16(whh1 + (64 + e) * DBn + koff, w1n);
    __syncthreads();   // barrier A

#if __has_builtin(__builtin_amdgcn_s_setprio)
    __builtin_amdgcn_s_setprio(1);
#endif
    const int n = nsh;
    const int C = (n + Kc - 1) >> 5;
    v2f h1a[8];
    #pragma unroll
    for (int q = 0; q < 8; ++q) h1a[q] = (v2f){0.0f, 0.0f};
    float h1self = 0.0f;
    for (int c = 0; c < C + 3; ++c) {
      if (c < C) {
        float* ring = &h1r_[c & 1][0][0];
        const int t0 = c * Kc;
        for (int k = 0; k < Kc; k += 4) {
          float4 d4 = *(const float4*)&yd[t0 + k];   // batched dtime (1 b128 / 4 steps)
          #pragma unroll
          for (int u = 0; u < 4; ++u) {
            float d  = (u == 0) ? d4.x : (u == 1) ? d4.y : (u == 2) ? d4.z : d4.w;
            float ar = dot8b(w1r, h1a);
            float az = dot8b(w1z, h1a);
            float an = dot8b(w1n, h1a);
            ar = dppx8_add(ar);
            az = dppx8_add(az);
            an = dppx8_add(an);
            float r1 = sigmoid_f(fmaf(d, gs_r, gb_r) + ar);
            float z1 = sigmoid_f(fmaf(d, gs_z, gb_z) + az);
            float n1 = tanh_f(fmaf(d, gs_n, gb_n) + r1 * (an + bhh1n));
            h1self = fmaf(z1, h1self - n1, n1);
            ring[(k + u) * DBn + e] = h1self;
            __builtin_amdgcn_wave_barrier();
            ld16(&ring[(k + u) * DBn + koff], h1a);   // only dependent DS stage
          }
        }
      }
      __syncthreads();
    }
  } else if (w == 1) {
    // ======== setup: Wih2 half-rows ========
    const float* wih2 = Wih + ((kb * Ln + 1) * Gn) * DBn;
    v2f wa[8], wbv[8], wcv[8];
    ld16(wih2 + (     e) * DBn + koff, wa);
    ld16(wih2 + (32 + e) * DBn + koff, wbv);
    ld16(wih2 + (64 + e) * DBn + koff, wcv);
    __syncthreads();   // barrier A

    const int n = nsh;
    const int C = (n + Kc - 1) >> 5;
    for (int c = 0; c < C + 3; ++c) {
      if (c >= 1 && c <= C) {
        const int cp = c - 1;
        const float* hsrc = &h1r_[cp & 1][0][0];
        for (int k = 0; k < Kc; ++k) {
          v2f hb[8];
          ld16(&hsrc[k * DBn + koff], hb);
          float g0 = dot8(wa,  hb);
          float g1 = dot8(wbv, hb);
          float g2 = dot8(wcv, hb);
          g0 = dppx8_add(g0);
          g1 = dppx8_add(g1);
          g2 = dppx8_add(g2);
          float4 gv; gv.x = g0; gv.y = g1; gv.z = g2; gv.w = 0.0f;
          *(float4*)&gxr_[cp & 1][k][e][0] = gv;
        }
      }
      if (c >= 3) {
        const int cd = c - 3;                      // drain y for chunk cd
        if (cd < C && L < 32) {
          float4 p = *(const float4*)&vr_[cd & 1][L][0];
          yd[cd * Kc + L] = ((p.x + p.y) + (p.z + p.w)) + mb2v;
        }
      }
      __syncthreads();
    }
  } else {
    // ======== setup: Whh2 half-rows, mW1 half-column, biases, n==0 fallback ========
    const float* whh2  = Whh + ((kb * Ln + 1) * Gn) * DBn;
    const float* bih2p = bih + (kb * Ln + 1) * Gn;
    const float* bhh2p = bhh + (kb * Ln + 1) * Gn;
    v2f r2w[8], z2w[8], n2w[8], m1c[8];
    ld16(whh2 + (     e) * DBn + koff, r2w);
    ld16(whh2 + (32 + e) * DBn + koff, z2w);
    ld16(whh2 + (64 + e) * DBn + koff, n2w);
    #pragma unroll
    for (int q = 0; q < 8; ++q)
      m1c[q] = (v2f){ mW1[(kb * DBn + koff + 2*q)     * DBn + e],
                      mW1[(kb * DBn + koff + 2*q + 1) * DBn + e] };
    const float c2r   = bih2p[e]      + bhh2p[e];
    const float c2z   = bih2p[32 + e] + bhh2p[32 + e];
    const float bih2n = bih2p[64 + e];
    const float bhh2n = bhh2p[64 + e];
    const float mb1e  = mb1[kb * DBn + e];
    const float mW2h  = 0.5f * mW2[kb * DBn + e];   // 0.5: each e appears twice/row
    {
      float p = fmaxf(mb1e, 0.0f) * mW2h;
      p = dpp_row_sum16(p);
      if ((L & 15) == 15) y0f[L >> 4] = p;
    }
    __syncthreads();   // barrier A

#if __has_builtin(__builtin_amdgcn_s_setprio)
    __builtin_amdgcn_s_setprio(1);
#endif
    const int n = nsh;
    const int C = (n + Kc - 1) >> 5;
    v2f h2A[8], h2B[8];
    #pragma unroll
    for (int q = 0; q < 8; ++q) { h2A[q] = (v2f){0.0f, 0.0f}; h2B[q] = (v2f){0.0f, 0.0f}; }
    float h2self = 0.0f;

#define L2_STEP(K, CUR, NXT)                                                   \
    {                                                                          \
      float4 g = *(const float4*)&gxr_[cc & 1][(K)][e][0];                     \
      float cr = dot8b(r2w, CUR);                                              \
      float cz = dot8b(z2w, CUR);                                              \
      float cn = dot8b(n2w, CUR);                                              \
      cr = dppx8_add(cr);                                                      \
      cz = dppx8_add(cz);                                                      \
      cn = dppx8_add(cn);                                                      \
      float r2v = sigmoid_f(g.x + cr + c2r);                                   \
      float z2v = sigmoid_f(g.y + cz + c2z);                                   \
      float n2v = tanh_f(g.z + bih2n + r2v * (cn + bhh2n));                    \
      float h2new = fmaf(z2v, h2self - n2v, n2v);                              \
      h2b[e] = h2new;                                                          \
      __builtin_amdgcn_wave_barrier();                                         \
      ld16(&h2b[koff], NXT);                                                   \
      if ((K) >= 1) {                                                          \
        float mh = dot8(m1c, CUR);                                             \
        mh = dppx8_add(mh);                                                    \
        float v = fmaxf(mh + mb1e, 0.0f) * mW2h;                               \
        v = dpp_row_sum16(v);                                                  \
        if ((L & 15) == 15) vr_[cc & 1][(K) - 1][L >> 4] = v;                  \
      }                                                                        \
      h2self = h2new;                                                          \
    }

    for (int c = 0; c < C + 3; ++c) {
      if (c >= 2 && c <= C + 1) {
        const int cc = c - 2;
        for (int k = 0; k < Kc; k += 2) {
          L2_STEP(k,     h2A, h2B)
          L2_STEP(k + 1, h2B, h2A)
        }
        // tail: MLP for step cc*Kc+Kc-1 from h2A
        {
          float mh = dot8(m1c, h2A);
          mh = dppx8_add(mh);
          float v = fmaxf(mh + mb1e, 0.0f) * mW2h;
          v = dpp_row_sum16(v);
          if ((L & 15) == 15) vr_[cc & 1][Kc - 1][L >> 4] = v;
        }
      }
      __syncthreads();
    }
#undef L2_STEP
  }

  // ================= joint epilogue =================
  const int n = nsh;
  float ylast;
  if (n > 0) {
    ylast = yd[n - 1];
  } else {
    float4 p = *(const float4*)&y0f[0];
    ylast = ((p.x + p.y) + (p.z + p.w)) + mb2v;
  }
  for (int t = n + tid; t < Tn; t += 192) yd[t] = ylast;
  __syncthreads();

  float* orow = out + (kb * Bn + b) * Tn;
  for (int q = tid; q < Tn / 4; q += 192)
    ((float4*)orow)[q] = ((const float4*)yd)[q];
}

extern "C" void kernel_launch(void* const* d_in, const int* in_sizes, int n_in,
                              void* d_out, int out_size, void* d_ws, size_t ws_size,
                              hipStream_t stream) {
  const int*   band_ids = (const int*)  d_in[0];
  const float* dtime    = (const float*)d_in[1];
  const float* z_last   = (const float*)d_in[2];
  const float* projW    = (const float*)d_in[3];
  const float* projB    = (const float*)d_in[4];
  const float* Wih      = (const float*)d_in[5];
  const float* Whh      = (const float*)d_in[6];
  const float* bihp     = (const float*)d_in[7];
  const float* bhhp     = (const float*)d_in[8];
  const float* mW1      = (const float*)d_in[9];
  const float* mb1      = (const float*)d_in[10];
  const float* mW2      = (const float*)d_in[11];
  const float* mb2      = (const float*)d_in[12];
  float* out = (float*)d_out;
  rnn_decoder<<<dim3(Bn * 2), dim3(192), 0, stream>>>(
      band_ids, dtime, z_last, projW, projB, Wih, Whh, bihp, bhhp,
      mW1, mb1, mW2, mb2, out);
}